// Round 9
// baseline (1285.914 us; speedup 1.0000x reference)
//
#include <hip/hip_runtime.h>
#include <math.h>

// Problem constants
#define BB 32768
#define DD 64
#define CC 64
#define HH 1024
#define LL 6
#define SPLIT 32
#define NIN 96
#define EPSV 1e-5f

typedef short short8 __attribute__((ext_vector_type(8)));
typedef float f32x4 __attribute__((ext_vector_type(4)));
typedef unsigned short u16;

// fp32 -> bf16 round-to-nearest-even (finite inputs)
__device__ __forceinline__ u16 f2bf(float f) {
    union { float f; unsigned int u; } c; c.f = f;
    unsigned int u = c.u + 0x7FFFu + ((c.u >> 16) & 1u);
    return (u16)(u >> 16);
}

__device__ __forceinline__ void gl_lds16(const u16* g, u16* l) {
    __builtin_amdgcn_global_load_lds(
        (const __attribute__((address_space(1))) unsigned int*)g,
        (__attribute__((address_space(3))) unsigned int*)l, 16, 0, 0);
}

// ---------------------------------------------------------------------------
// Transpose + convert: dst[c][r] (bf16, row stride Rpad) = src[r][c] (f32)
// ---------------------------------------------------------------------------
__global__ void transpose_cvt_kernel(const float* __restrict__ src, u16* __restrict__ dst,
                                     int R, int C, int Rpad,
                                     long long sstride, long long dstride)
{
    __shared__ float tile[32][33];
    const float* s = src + (size_t)blockIdx.z * sstride;
    u16* d = dst + (size_t)blockIdx.z * dstride;
    int r0 = blockIdx.x * 32, c0 = blockIdx.y * 32;
    int tc = threadIdx.x & 31, tr = threadIdx.x >> 5;   // 32 x 8
#pragma unroll
    for (int i = 0; i < 4; ++i) {
        int r = r0 + tr + i * 8;
        tile[tr + i * 8][tc] = (r < R) ? s[(size_t)r * C + c0 + tc] : 0.f;
    }
    __syncthreads();
#pragma unroll
    for (int i = 0; i < 4; ++i) {
        int cc = tr + i * 8;
        d[(size_t)(c0 + cc) * Rpad + r0 + tc] = f2bf(tile[tc][cc]);
    }
}

// ---------------------------------------------------------------------------
// One-time: fill Ain cond columns (32..95) + zero pad (96..127), all BB rows.
// ---------------------------------------------------------------------------
__global__ __launch_bounds__(256)
void init_ain_cond_kernel(const float* __restrict__ cond, u16* __restrict__ Ain)
{
    int t = blockIdx.x * 256 + threadIdx.x;   // over BB*96
    int c = t % 96, r = t / 96;
    Ain[(size_t)r * 128 + 32 + c] = (c < CC) ? f2bf(cond[(size_t)r * CC + c]) : (u16)0;
}

// One-time (layer 0): fill Ain keep columns (0..31) from x.
__global__ __launch_bounds__(256)
void build_keep_kernel(const float* __restrict__ x, u16* __restrict__ Ain, int keep_off)
{
    int t = blockIdx.x * 256 + threadIdx.x;   // over BB*32
    int c = t & 31, r = t >> 5;
    Ain[(size_t)r * 128 + c] = f2bf(x[(size_t)r * DD + 2 * c + keep_off]);
}

// ---------------------------------------------------------------------------
// Tiled bf16 MFMA GEMM: C = relu(A @ Bt^T + bias), N = 1024 fixed.
// 128x128 tile, 4 waves (2x2, wave tile 64x64), BK=32 double-buffered LDS
// (32 KB), one barrier per K-iter, 4 blocks/CU co-resident
// (__launch_bounds__(256,4): acc 64 + arch ~56 <= 128 regs/wave).
// XCD swizzle: 8 col-blocks sweep fastest within an XCD (W2 fits per-XCD L2).
// ---------------------------------------------------------------------------
__global__ __launch_bounds__(256, 4)
void gemm_tiled(const u16* __restrict__ A,    // [M][K] bf16 row-major (chunk-local)
                const u16* __restrict__ Bt,   // [1024][K] bf16 N-major
                const float* __restrict__ bias,
                u16* __restrict__ Cc,         // [M][1024] bf16 out
                int K)
{
    __shared__ u16 sA[2][8 * 512];     // 8 KB per buffer
    __shared__ u16 sB[2][8 * 512];

    const int t = threadIdx.x;
    const int w = t >> 6, lane = t & 63;
    const int lane16 = lane & 15, quad = lane >> 4;
    const int wm = w >> 1, wn = w & 1;          // 2 x 2 waves

    // XCD swizzle: grid = nby x 8, col index fastest within an XCD
    int id = blockIdx.x;
    int nby = gridDim.x >> 3;
    int xcd = id & 7, slot = id >> 3;
    int bx = slot & 7, byq = slot >> 3;
    int by = xcd * (nby >> 3) + byq;
    const int bm = by * 128, bn = bx * 128;

    const int niter = K >> 5;

    // stage K-chunk it (16 entries: 8 A row-tiles + 8 B col-tiles; 4/wave)
    auto stage = [&](int it, int buf) {
        int k0 = it * 32;
#pragma unroll
        for (int i = 0; i < 4; ++i) {
            int e = w + i * 4;                 // wave-uniform
            if (e < 8) {
                const u16* g = A + (size_t)(bm + e * 16 + lane16) * K + k0 + quad * 8;
                gl_lds16(g, &sA[buf][e * 512]);
            } else {
                int j = e - 8;
                const u16* g = Bt + (size_t)(bn + j * 16 + lane16) * K + k0 + quad * 8;
                gl_lds16(g, &sB[buf][j * 512]);
            }
        }
    };

    f32x4 acc[4][4];
#pragma unroll
    for (int a = 0; a < 4; ++a)
#pragma unroll
        for (int b = 0; b < 4; ++b) acc[a][b] = (f32x4){0.f, 0.f, 0.f, 0.f};

    stage(0, 0);
    for (int it = 0; it < niter; ++it) {
        const int buf = it & 1;
        __syncthreads();                       // drains stage(it)
        if (it + 1 < niter) stage(it + 1, buf ^ 1);
        short8 af[4], bf[4];
#pragma unroll
        for (int a = 0; a < 4; ++a)
            af[a] = *(const short8*)(&sA[buf][(wm * 4 + a) * 512 + lane * 8]);
#pragma unroll
        for (int b = 0; b < 4; ++b)
            bf[b] = *(const short8*)(&sB[buf][(wn * 4 + b) * 512 + lane * 8]);
#pragma unroll
        for (int a = 0; a < 4; ++a)
#pragma unroll
            for (int b = 0; b < 4; ++b)
                acc[a][b] = __builtin_amdgcn_mfma_f32_16x16x32_bf16(af[a], bf[b], acc[a][b], 0, 0, 0);
    }
    __syncthreads();                           // all compute done; LDS reusable

    // ---- epilogue: bias+relu+f2bf via per-wave scratch, coalesced stores ----
    constexpr int ES = 72;                     // shorts per scratch row
    float bv[4];
#pragma unroll
    for (int b = 0; b < 4; ++b) bv[b] = bias[bn + wn * 64 + b * 16 + lane16];
    u16* scr = ((u16*)sA) + w * (16 * ES);     // 4 waves x 2304 B in 16 KB region
#pragma unroll
    for (int a = 0; a < 4; ++a) {
#pragma unroll
        for (int b = 0; b < 4; ++b)
#pragma unroll
            for (int r = 0; r < 4; ++r) {
                float v = fmaxf(acc[a][b][r] + bv[b], 0.f);
                scr[(quad * 4 + r) * ES + b * 16 + lane16] = f2bf(v);
            }
#pragma unroll
        for (int ch = 0; ch < 2; ++ch) {
            int row = ch * 8 + (lane >> 3), colc = (lane & 7) * 8;
            short8 v = *(const short8*)(scr + row * ES + colc);
            *(short8*)(Cc + (size_t)(bm + wm * 64 + a * 16 + row) * 1024 + bn + wn * 64 + colc) = v;
        }
    }
}

// ---------------------------------------------------------------------------
// Fused GEMM3 + coupling. BM=128, 8 waves (4x2), wave tile 32x32.
// st tile (128x64) in LDS (stride 66).
// ---------------------------------------------------------------------------
__global__ __launch_bounds__(512)
void gemm3_coupling(const u16* __restrict__ A,    // h2 chunk [CH][1024]
                    const u16* __restrict__ Bt,   // wst [64][1024]
                    const float* __restrict__ bs, const float* __restrict__ bt,
                    float* __restrict__ x, float* __restrict__ log_det,
                    float* __restrict__ stat_sum, float* __restrict__ stat_sumsq,
                    int keep_off, int row0)
{
    constexpr int K = HH;
    constexpr int ST_STRIDE = 66;
    __shared__ float sst[128 * ST_STRIDE];           // 33.8 KB (aliased for staging)
    __shared__ float ssum[8][64], ssum2[8][64];
    u16* lds = (u16*)sst;

    const int t = threadIdx.x;
    const int w = t >> 6, lane = t & 63;
    const int lane16 = lane & 15, quad = lane >> 4;
    const int wm = w >> 1, wn = w & 1;               // 4 x 2 waves
    const int bm = blockIdx.x * 128;

    u16* ldsA = lds;                                 // 16 entries
    u16* ldsB = lds + 16 * 512;                      // 8 entries

    f32x4 acc[2][2];
#pragma unroll
    for (int a = 0; a < 2; ++a)
#pragma unroll
        for (int b = 0; b < 2; ++b) acc[a][b] = (f32x4){0.f, 0.f, 0.f, 0.f};

    for (int k0 = 0; k0 < K; k0 += 64) {
        for (int e = w; e < 16; e += 8) {            // A: 2 per wave
            int s = e >> 3, i = e & 7;
            const u16* g = A + (size_t)(bm + i * 16 + lane16) * K + (k0 + s * 32 + quad * 8);
            gl_lds16(g, ldsA + e * 512);
        }
        {                                            // B: 1 per wave (e = w < 8)
            int s = w >> 2, j = w & 3;
            const u16* g = Bt + (size_t)(j * 16 + lane16) * K + (k0 + s * 32 + quad * 8);
            gl_lds16(g, ldsB + w * 512);
        }
        __syncthreads();
#pragma unroll
        for (int s = 0; s < 2; ++s) {
            short8 af[2], bfr[2];
#pragma unroll
            for (int a = 0; a < 2; ++a)
                af[a] = *(const short8*)(ldsA + ((s * 8 + wm * 2 + a) * 512) + lane * 8);
#pragma unroll
            for (int b = 0; b < 2; ++b)
                bfr[b] = *(const short8*)(ldsB + ((s * 4 + wn * 2 + b) * 512) + lane * 8);
#pragma unroll
            for (int a = 0; a < 2; ++a)
#pragma unroll
                for (int b = 0; b < 2; ++b)
                    acc[a][b] = __builtin_amdgcn_mfma_f32_16x16x32_bf16(af[a], bfr[b], acc[a][b], 0, 0, 0);
        }
        __syncthreads();
    }

    // scatter acc -> LDS st tile (128 x 64)
#pragma unroll
    for (int a = 0; a < 2; ++a)
#pragma unroll
        for (int b = 0; b < 2; ++b)
#pragma unroll
            for (int r = 0; r < 4; ++r) {
                int row = wm * 32 + a * 16 + quad * 4 + r;
                int col = wn * 32 + b * 16 + lane16;
                sst[row * ST_STRIDE + col] = acc[a][b][r];
            }
    __syncthreads();

    // coupling: wave w -> rows [w*16, w*16+16), lane = feature f
    const int f = lane;
    const bool is_chg = ((f & 1) != keep_off);
    const int j = f >> 1;
    float bsj = 0.f, btj = 0.f;
    if (is_chg) { bsj = bs[j]; btj = bt[j]; }

    float lsum = 0.f, lsum2 = 0.f;
    for (int i = 0; i < 16; ++i) {
        int crow = w * 16 + i;
        int grow = row0 + bm + crow;
        float xv = x[(size_t)grow * DD + f];
        float ld = 0.f;
        if (is_chg) {
            float s_raw = sst[crow * ST_STRIDE + j];
            float t_raw = sst[crow * ST_STRIDE + SPLIT + j];
            float ls = tanhf(s_raw + bsj);
            float tv = t_raw + btj;
            xv = xv * expf(ls) + tv;
            x[(size_t)grow * DD + f] = xv;
            ld = ls;
        }
        for (int off = 32; off > 0; off >>= 1) ld += __shfl_down(ld, off, 64);
        if (f == 0) log_det[grow] += ld;
        lsum  += xv;
        lsum2 += xv * xv;
    }

    ssum[w][f]  = lsum;
    ssum2[w][f] = lsum2;
    __syncthreads();
    if (t < 64) {
        float a = 0.f, b = 0.f;
#pragma unroll
        for (int g = 0; g < 8; ++g) { a += ssum[g][t]; b += ssum2[g][t]; }
        atomicAdd(stat_sum + t, a);
        atomicAdd(stat_sumsq + t, b);
    }
}

// ---------------------------------------------------------------------------
// BN normalize (scale/shift computed in-block from raw stats — no separate
// finalize dispatch); optionally writes bf16 keep-columns of next Ain.
// ---------------------------------------------------------------------------
__global__ __launch_bounds__(256)
void normalize_kernel(const float* __restrict__ xin, float* __restrict__ xout,
                      const float* __restrict__ stat_sum, const float* __restrict__ stat_sumsq,
                      const float* __restrict__ bn_w, const float* __restrict__ bn_b,
                      float* __restrict__ log_det,
                      u16* __restrict__ Ain, int off_next)
{
    __shared__ float sscale[64], sshift[64], scsum;
    int t = threadIdx.x;
    if (t < 64) {
        const float invB = 1.f / (float)BB;
        float mean = stat_sum[t] * invB;
        float var  = stat_sumsq[t] * invB - mean * mean;
        float inv  = rsqrtf(var + EPSV);
        float wv   = bn_w[t];
        float sc   = inv * wv;
        sscale[t] = sc;
        sshift[t] = bn_b[t] - mean * sc;
        float lg = logf(fabsf(wv));
        for (int off = 32; off > 0; off >>= 1) lg += __shfl_down(lg, off, 64);
        if (t == 0) scsum = lg;
    }
    __syncthreads();

    int idx = blockIdx.x * blockDim.x + t;     // over B*64/4
    int f0 = (idx & 15) * 4;
    int row = idx >> 4;
    float4 v = ((const float4*)xin)[idx];
    v.x = v.x * sscale[f0 + 0] + sshift[f0 + 0];
    v.y = v.y * sscale[f0 + 1] + sshift[f0 + 1];
    v.z = v.z * sscale[f0 + 2] + sshift[f0 + 2];
    v.w = v.w * sscale[f0 + 3] + sshift[f0 + 3];
    ((float4*)xout)[idx] = v;
    if ((idx & 15) == 0) log_det[row] += scsum;
    if (Ain) {
        float a0 = off_next ? v.y : v.x;
        float a1 = off_next ? v.w : v.z;
        ushort2 u; u.x = f2bf(a0); u.y = f2bf(a1);
        *(ushort2*)(Ain + (size_t)row * 128 + (f0 >> 1)) = u;
    }
}

// ---------------------------------------------------------------------------
extern "C" void kernel_launch(void* const* d_in, const int* in_sizes, int n_in,
                              void* d_out, int out_size, void* d_ws, size_t ws_size,
                              hipStream_t stream)
{
    const float* z    = (const float*)d_in[0];
    const float* cond = (const float*)d_in[1];
    const float* W1   = (const float*)d_in[2];
    const float* b1   = (const float*)d_in[3];
    const float* W2   = (const float*)d_in[4];
    const float* b2   = (const float*)d_in[5];
    const float* Ws   = (const float*)d_in[6];
    const float* bs   = (const float*)d_in[7];
    const float* Wt   = (const float*)d_in[8];
    const float* bt   = (const float*)d_in[9];
    const float* bn_w = (const float*)d_in[10];
    const float* bn_b = (const float*)d_in[11];

    float* out_x  = (float*)d_out;
    float* out_ld = out_x + (size_t)BB * DD;

    // ---- workspace: fixed part ~30.5 MB + h1/h2 (CH*4 KB) ----
    char* p = (char*)d_ws;
    size_t used = 0;
    auto alloc = [&](size_t bytes) { void* q = p + used; used += (bytes + 255) & ~(size_t)255; return q; };

    float* xbuf = (float*)alloc((size_t)BB * DD * 4);
    u16*   w1t  = (u16*)alloc((size_t)LL * HH * 128 * 2);
    u16*   w2t  = (u16*)alloc((size_t)LL * HH * HH * 2);
    u16*   wstt = (u16*)alloc((size_t)LL * 64 * HH * 2);
    u16*   Ain  = (u16*)alloc((size_t)BB * 128 * 2);
    float* stat_sum   = (float*)alloc(64 * 4);
    float* stat_sumsq = (float*)alloc(64 * 4);

    int CH = BB;
    while (CH > 8192 && used + (size_t)CH * 4096 + 4096 > ws_size) CH >>= 1;
    u16* h1 = (u16*)alloc((size_t)CH * HH * 2);
    u16* h2 = (u16*)alloc((size_t)CH * HH * 2);

    // ---- init ----
    hipMemcpyAsync(xbuf, z, (size_t)BB * DD * sizeof(float), hipMemcpyDeviceToDevice, stream);
    hipMemsetAsync(out_ld, 0, (size_t)BB * sizeof(float), stream);

    transpose_cvt_kernel<<<dim3(128/32, HH/32, LL), 256, 0, stream>>>(
        W1, w1t, NIN, HH, 128, (long long)NIN * HH, (long long)HH * 128);
    transpose_cvt_kernel<<<dim3(HH/32, HH/32, LL), 256, 0, stream>>>(
        W2, w2t, HH, HH, HH, (long long)HH * HH, (long long)HH * HH);
    transpose_cvt_kernel<<<dim3(HH/32, SPLIT/32, LL), 256, 0, stream>>>(
        Ws, wstt, HH, SPLIT, HH, (long long)HH * SPLIT, (long long)64 * HH);
    transpose_cvt_kernel<<<dim3(HH/32, SPLIT/32, LL), 256, 0, stream>>>(
        Wt, wstt + (size_t)SPLIT * HH, HH, SPLIT, HH, (long long)HH * SPLIT, (long long)64 * HH);

    init_ain_cond_kernel<<<BB * 96 / 256, 256, 0, stream>>>(cond, Ain);
    build_keep_kernel<<<BB * 32 / 256, 256, 0, stream>>>(xbuf, Ain, 0);

    for (int l = 0; l < LL; ++l) {
        const int off = l & 1;
        hipMemsetAsync(stat_sum, 0, 2 * 64 * sizeof(float), stream);

        for (int c = 0; c < BB / CH; ++c) {
            const int row0 = c * CH;

            // GEMM1: h1 = relu(Ain @ W1t^T + b1)   M=CH, K=128
            gemm_tiled<<<(CH / 128) * 8, 256, 0, stream>>>(
                Ain + (size_t)row0 * 128, w1t + (size_t)l * HH * 128,
                b1 + (size_t)l * HH, h1, 128);

            // GEMM2: h2 = relu(h1 @ W2t^T + b2)    M=CH, K=1024
            gemm_tiled<<<(CH / 128) * 8, 256, 0, stream>>>(
                h1, w2t + (size_t)l * HH * HH,
                b2 + (size_t)l * HH, h2, HH);

            // GEMM3 + coupling fused (BM=128)
            gemm3_coupling<<<CH / 128, 512, 0, stream>>>(
                h2, wstt + (size_t)l * 64 * HH,
                bs + (size_t)l * SPLIT, bt + (size_t)l * SPLIT,
                xbuf, out_ld, stat_sum, stat_sumsq, off, row0);
        }

        float* xout = (l == LL - 1) ? out_x : xbuf;
        u16* ain_next = (l < LL - 1) ? Ain : nullptr;
        normalize_kernel<<<(BB * DD / 4) / 256, 256, 0, stream>>>(
            xbuf, xout, stat_sum, stat_sumsq,
            bn_w + (size_t)l * DD, bn_b + (size_t)l * DD,
            out_ld, ain_next, (l + 1) & 1);
    }
}

// Round 10
// 1092.369 us; speedup vs baseline: 1.1772x; 1.1772x over previous
//
#include <hip/hip_runtime.h>
#include <math.h>

// Problem constants
#define BB 32768
#define DD 64
#define CC 64
#define HH 1024
#define LL 6
#define SPLIT 32
#define NIN 96
#define EPSV 1e-5f

typedef short short8 __attribute__((ext_vector_type(8)));
typedef float f32x4 __attribute__((ext_vector_type(4)));
typedef unsigned short u16;

// fp32 -> bf16 round-to-nearest-even (finite inputs)
__device__ __forceinline__ u16 f2bf(float f) {
    union { float f; unsigned int u; } c; c.f = f;
    unsigned int u = c.u + 0x7FFFu + ((c.u >> 16) & 1u);
    return (u16)(u >> 16);
}

__device__ __forceinline__ void gl_lds16(const u16* g, u16* l) {
    __builtin_amdgcn_global_load_lds(
        (const __attribute__((address_space(1))) unsigned int*)g,
        (__attribute__((address_space(3))) unsigned int*)l, 16, 0, 0);
}

// ---------------------------------------------------------------------------
// Transpose + convert: dst[c][r] (bf16, row stride Rpad) = src[r][c] (f32)
// ---------------------------------------------------------------------------
__global__ void transpose_cvt_kernel(const float* __restrict__ src, u16* __restrict__ dst,
                                     int R, int C, int Rpad,
                                     long long sstride, long long dstride)
{
    __shared__ float tile[32][33];
    const float* s = src + (size_t)blockIdx.z * sstride;
    u16* d = dst + (size_t)blockIdx.z * dstride;
    int r0 = blockIdx.x * 32, c0 = blockIdx.y * 32;
    int tc = threadIdx.x & 31, tr = threadIdx.x >> 5;   // 32 x 8
#pragma unroll
    for (int i = 0; i < 4; ++i) {
        int r = r0 + tr + i * 8;
        tile[tr + i * 8][tc] = (r < R) ? s[(size_t)r * C + c0 + tc] : 0.f;
    }
    __syncthreads();
#pragma unroll
    for (int i = 0; i < 4; ++i) {
        int cc = tr + i * 8;
        d[(size_t)(c0 + cc) * Rpad + r0 + tc] = f2bf(tile[tc][cc]);
    }
}

// ---------------------------------------------------------------------------
// One-time: fill Ain cond columns (32..95) + zero pad (96..127), all BB rows.
// ---------------------------------------------------------------------------
__global__ __launch_bounds__(256)
void init_ain_cond_kernel(const float* __restrict__ cond, u16* __restrict__ Ain)
{
    int t = blockIdx.x * 256 + threadIdx.x;   // over BB*96
    int c = t % 96, r = t / 96;
    Ain[(size_t)r * 128 + 32 + c] = (c < CC) ? f2bf(cond[(size_t)r * CC + c]) : (u16)0;
}

// One-time (layer 0): fill Ain keep columns (0..31) from x.
__global__ __launch_bounds__(256)
void build_keep_kernel(const float* __restrict__ x, u16* __restrict__ Ain, int keep_off)
{
    int t = blockIdx.x * 256 + threadIdx.x;   // over BB*32
    int c = t & 31, r = t >> 5;
    Ain[(size_t)r * 128 + c] = f2bf(x[(size_t)r * DD + 2 * c + keep_off]);
}

// ---------------------------------------------------------------------------
// Tiled bf16 MFMA GEMM: C = relu(A @ Bt^T + bias), N = 1024 fixed.
// R8 shape (best measured): 128 rows x 256 cols, 8 waves (2x4, wave tile
// 64x64), BK=32 double-buffered LDS (48 KB), one barrier per K-iter,
// __launch_bounds__(512,4); 3 blocks/CU (LDS-limited).
// ---------------------------------------------------------------------------
__global__ __launch_bounds__(512, 4)
void gemm_tiled(const u16* __restrict__ A,    // [M][K] bf16 row-major (chunk-local)
                const u16* __restrict__ Bt,   // [1024][K] bf16 N-major
                const float* __restrict__ bias,
                u16* __restrict__ Cc,         // [M][1024] bf16 out
                int K)
{
    __shared__ u16 sA[2][8 * 512];     // 16 KB
    __shared__ u16 sB[2][16 * 512];    // 32 KB

    const int t = threadIdx.x;
    const int w = t >> 6, lane = t & 63;
    const int lane16 = lane & 15, quad = lane >> 4;
    const int wm = w >> 2, wn = w & 3;          // 2 x 4 waves

    // XCD swizzle: grid = nby x 4, col index fastest within an XCD
    int id = blockIdx.x;
    int nby = gridDim.x >> 2;
    int xcd = id & 7, slot = id >> 3;
    int bx = slot & 3, byq = slot >> 2;
    int by = xcd * (nby >> 3) + byq;
    const int bm = by * 128, bn = bx * 256;

    const int niter = K >> 5;

    // stage K-chunk it (24 entries: 8 A row-tiles + 16 B col-tiles; 3/wave)
    auto stage = [&](int it, int buf) {
        int k0 = it * 32;
#pragma unroll
        for (int e3 = 0; e3 < 3; ++e3) {
            int e = w + e3 * 8;
            if (e < 8) {
                const u16* g = A + (size_t)(bm + e * 16 + lane16) * K + k0 + quad * 8;
                gl_lds16(g, &sA[buf][e * 512]);
            } else {
                int j = e - 8;
                const u16* g = Bt + (size_t)(bn + j * 16 + lane16) * K + k0 + quad * 8;
                gl_lds16(g, &sB[buf][j * 512]);
            }
        }
    };

    f32x4 acc[4][4];
#pragma unroll
    for (int a = 0; a < 4; ++a)
#pragma unroll
        for (int b = 0; b < 4; ++b) acc[a][b] = (f32x4){0.f, 0.f, 0.f, 0.f};

    stage(0, 0);
    for (int it = 0; it < niter; ++it) {
        const int buf = it & 1;
        __syncthreads();                       // drains stage(it)
        if (it + 1 < niter) stage(it + 1, buf ^ 1);
        short8 af[4], bf[4];
#pragma unroll
        for (int a = 0; a < 4; ++a)
            af[a] = *(const short8*)(&sA[buf][(wm * 4 + a) * 512 + lane * 8]);
#pragma unroll
        for (int b = 0; b < 4; ++b)
            bf[b] = *(const short8*)(&sB[buf][(wn * 4 + b) * 512 + lane * 8]);
#pragma unroll
        for (int a = 0; a < 4; ++a)
#pragma unroll
            for (int b = 0; b < 4; ++b)
                acc[a][b] = __builtin_amdgcn_mfma_f32_16x16x32_bf16(af[a], bf[b], acc[a][b], 0, 0, 0);
    }
    __syncthreads();                           // all compute done; LDS reusable

    // ---- epilogue: bias+relu+f2bf via per-wave scratch, coalesced stores ----
    constexpr int ES = 72;                     // shorts per scratch row
    float bv[4];
#pragma unroll
    for (int b = 0; b < 4; ++b) bv[b] = bias[bn + wn * 64 + b * 16 + lane16];
    u16* scr = ((u16*)sB) + w * (16 * ES);     // 2304 B per wave
#pragma unroll
    for (int a = 0; a < 4; ++a) {
#pragma unroll
        for (int b = 0; b < 4; ++b)
#pragma unroll
            for (int r = 0; r < 4; ++r) {
                float v = fmaxf(acc[a][b][r] + bv[b], 0.f);
                scr[(quad * 4 + r) * ES + b * 16 + lane16] = f2bf(v);
            }
#pragma unroll
        for (int ch = 0; ch < 2; ++ch) {
            int row = ch * 8 + (lane >> 3), colc = (lane & 7) * 8;
            short8 v = *(const short8*)(scr + row * ES + colc);
            *(short8*)(Cc + (size_t)(bm + wm * 64 + a * 16 + row) * 1024 + bn + wn * 64 + colc) = v;
        }
    }
}

// ---------------------------------------------------------------------------
// Fused GEMM3 + coupling. BM=128, 8 waves (4x2), wave tile 32x32.
// BK=64 DOUBLE-BUFFERED staging (one barrier per K-iter; this kernel runs at
// ~1 block/CU so exposed barriers were costly). st tile aliases the stage
// buffers after the final barrier.
// ---------------------------------------------------------------------------
__global__ __launch_bounds__(512)
void gemm3_coupling(const u16* __restrict__ A,    // h2 chunk [CH][1024]
                    const u16* __restrict__ Bt,   // wst [64][1024]
                    const float* __restrict__ bs, const float* __restrict__ bt,
                    float* __restrict__ x, float* __restrict__ log_det,
                    float* __restrict__ stat_sum, float* __restrict__ stat_sumsq,
                    int keep_off, int row0)
{
    constexpr int ST_STRIDE = 66;
    __shared__ u16 stg[2][24 * 512];                 // 48 KB (aliased by sst)
    __shared__ float ssum[8][64], ssum2[8][64];
    float* sst = (float*)stg;                        // 128*66*4 = 33.8 KB < 48 KB

    const int t = threadIdx.x;
    const int w = t >> 6, lane = t & 63;
    const int lane16 = lane & 15, quad = lane >> 4;
    const int wm = w >> 1, wn = w & 1;               // 4 x 2 waves
    const int bm = blockIdx.x * 128;

    // stage K-iter it: 24 entries (A: e=0..15 -> s=e>>3,i=e&7; B: 16..23)
    auto stage = [&](int it, int buf) {
        int k0 = it * 64;
#pragma unroll
        for (int p = 0; p < 3; ++p) {
            int e = w + p * 8;
            if (e < 16) {
                int s = e >> 3, i = e & 7;
                const u16* g = A + (size_t)(bm + i * 16 + lane16) * HH + (k0 + s * 32 + quad * 8);
                gl_lds16(g, &stg[buf][e * 512]);
            } else {
                int j2 = e - 16, s = j2 >> 2, j = j2 & 3;
                const u16* g = Bt + (size_t)(j * 16 + lane16) * HH + (k0 + s * 32 + quad * 8);
                gl_lds16(g, &stg[buf][e * 512]);
            }
        }
    };

    f32x4 acc[2][2];
#pragma unroll
    for (int a = 0; a < 2; ++a)
#pragma unroll
        for (int b = 0; b < 2; ++b) acc[a][b] = (f32x4){0.f, 0.f, 0.f, 0.f};

    stage(0, 0);
    for (int it = 0; it < 16; ++it) {
        const int buf = it & 1;
        __syncthreads();
        if (it + 1 < 16) stage(it + 1, buf ^ 1);
        u16* ldsA = stg[buf];
        u16* ldsB = stg[buf] + 16 * 512;
#pragma unroll
        for (int s = 0; s < 2; ++s) {
            short8 af[2], bfr[2];
#pragma unroll
            for (int a = 0; a < 2; ++a)
                af[a] = *(const short8*)(ldsA + ((s * 8 + wm * 2 + a) * 512) + lane * 8);
#pragma unroll
            for (int b = 0; b < 2; ++b)
                bfr[b] = *(const short8*)(ldsB + ((s * 4 + wn * 2 + b) * 512) + lane * 8);
#pragma unroll
            for (int a = 0; a < 2; ++a)
#pragma unroll
                for (int b = 0; b < 2; ++b)
                    acc[a][b] = __builtin_amdgcn_mfma_f32_16x16x32_bf16(af[a], bfr[b], acc[a][b], 0, 0, 0);
        }
    }
    __syncthreads();                                 // staging done; alias as sst

    // scatter acc -> LDS st tile (128 x 64)
#pragma unroll
    for (int a = 0; a < 2; ++a)
#pragma unroll
        for (int b = 0; b < 2; ++b)
#pragma unroll
            for (int r = 0; r < 4; ++r) {
                int row = wm * 32 + a * 16 + quad * 4 + r;
                int col = wn * 32 + b * 16 + lane16;
                sst[row * ST_STRIDE + col] = acc[a][b][r];
            }
    __syncthreads();

    // coupling: wave w -> rows [w*16, w*16+16), lane = feature f
    const int f = lane;
    const bool is_chg = ((f & 1) != keep_off);
    const int j = f >> 1;
    float bsj = 0.f, btj = 0.f;
    if (is_chg) { bsj = bs[j]; btj = bt[j]; }

    float lsum = 0.f, lsum2 = 0.f;
    for (int i = 0; i < 16; ++i) {
        int crow = w * 16 + i;
        int grow = row0 + bm + crow;
        float xv = x[(size_t)grow * DD + f];
        float ld = 0.f;
        if (is_chg) {
            float s_raw = sst[crow * ST_STRIDE + j];
            float t_raw = sst[crow * ST_STRIDE + SPLIT + j];
            float ls = tanhf(s_raw + bsj);
            float tv = t_raw + btj;
            xv = xv * expf(ls) + tv;
            x[(size_t)grow * DD + f] = xv;
            ld = ls;
        }
        for (int off = 32; off > 0; off >>= 1) ld += __shfl_down(ld, off, 64);
        if (f == 0) log_det[grow] += ld;
        lsum  += xv;
        lsum2 += xv * xv;
    }

    ssum[w][f]  = lsum;
    ssum2[w][f] = lsum2;
    __syncthreads();
    if (t < 64) {
        float a = 0.f, b = 0.f;
#pragma unroll
        for (int g = 0; g < 8; ++g) { a += ssum[g][t]; b += ssum2[g][t]; }
        atomicAdd(stat_sum + t, a);
        atomicAdd(stat_sumsq + t, b);
    }
}

// ---------------------------------------------------------------------------
// BN normalize (scale/shift computed in-block from raw stats); optionally
// writes bf16 keep-columns of next layer's Ain.
// ---------------------------------------------------------------------------
__global__ __launch_bounds__(256)
void normalize_kernel(const float* __restrict__ xin, float* __restrict__ xout,
                      const float* __restrict__ stat_sum, const float* __restrict__ stat_sumsq,
                      const float* __restrict__ bn_w, const float* __restrict__ bn_b,
                      float* __restrict__ log_det,
                      u16* __restrict__ Ain, int off_next)
{
    __shared__ float sscale[64], sshift[64], scsum;
    int t = threadIdx.x;
    if (t < 64) {
        const float invB = 1.f / (float)BB;
        float mean = stat_sum[t] * invB;
        float var  = stat_sumsq[t] * invB - mean * mean;
        float inv  = rsqrtf(var + EPSV);
        float wv   = bn_w[t];
        float sc   = inv * wv;
        sscale[t] = sc;
        sshift[t] = bn_b[t] - mean * sc;
        float lg = logf(fabsf(wv));
        for (int off = 32; off > 0; off >>= 1) lg += __shfl_down(lg, off, 64);
        if (t == 0) scsum = lg;
    }
    __syncthreads();

    int idx = blockIdx.x * blockDim.x + t;     // over B*64/4
    int f0 = (idx & 15) * 4;
    int row = idx >> 4;
    float4 v = ((const float4*)xin)[idx];
    v.x = v.x * sscale[f0 + 0] + sshift[f0 + 0];
    v.y = v.y * sscale[f0 + 1] + sshift[f0 + 1];
    v.z = v.z * sscale[f0 + 2] + sshift[f0 + 2];
    v.w = v.w * sscale[f0 + 3] + sshift[f0 + 3];
    ((float4*)xout)[idx] = v;
    if ((idx & 15) == 0) log_det[row] += scsum;
    if (Ain) {
        float a0 = off_next ? v.y : v.x;
        float a1 = off_next ? v.w : v.z;
        ushort2 u; u.x = f2bf(a0); u.y = f2bf(a1);
        *(ushort2*)(Ain + (size_t)row * 128 + (f0 >> 1)) = u;
    }
}

// ---------------------------------------------------------------------------
extern "C" void kernel_launch(void* const* d_in, const int* in_sizes, int n_in,
                              void* d_out, int out_size, void* d_ws, size_t ws_size,
                              hipStream_t stream)
{
    const float* z    = (const float*)d_in[0];
    const float* cond = (const float*)d_in[1];
    const float* W1   = (const float*)d_in[2];
    const float* b1   = (const float*)d_in[3];
    const float* W2   = (const float*)d_in[4];
    const float* b2   = (const float*)d_in[5];
    const float* Ws   = (const float*)d_in[6];
    const float* bs   = (const float*)d_in[7];
    const float* Wt   = (const float*)d_in[8];
    const float* bt   = (const float*)d_in[9];
    const float* bn_w = (const float*)d_in[10];
    const float* bn_b = (const float*)d_in[11];

    float* out_x  = (float*)d_out;
    float* out_ld = out_x + (size_t)BB * DD;

    // ---- workspace: fixed part ~30.5 MB + h1/h2 (CH*4 KB) ----
    char* p = (char*)d_ws;
    size_t used = 0;
    auto alloc = [&](size_t bytes) { void* q = p + used; used += (bytes + 255) & ~(size_t)255; return q; };

    float* xbuf = (float*)alloc((size_t)BB * DD * 4);
    u16*   w1t  = (u16*)alloc((size_t)LL * HH * 128 * 2);
    u16*   w2t  = (u16*)alloc((size_t)LL * HH * HH * 2);
    u16*   wstt = (u16*)alloc((size_t)LL * 64 * HH * 2);
    u16*   Ain  = (u16*)alloc((size_t)BB * 128 * 2);
    float* stat_sum   = (float*)alloc(64 * 4);
    float* stat_sumsq = (float*)alloc(64 * 4);

    int CH = BB;
    while (CH > 8192 && used + (size_t)CH * 4096 + 4096 > ws_size) CH >>= 1;
    u16* h1 = (u16*)alloc((size_t)CH * HH * 2);
    u16* h2 = (u16*)alloc((size_t)CH * HH * 2);

    // ---- init ----
    hipMemcpyAsync(xbuf, z, (size_t)BB * DD * sizeof(float), hipMemcpyDeviceToDevice, stream);
    hipMemsetAsync(out_ld, 0, (size_t)BB * sizeof(float), stream);

    transpose_cvt_kernel<<<dim3(128/32, HH/32, LL), 256, 0, stream>>>(
        W1, w1t, NIN, HH, 128, (long long)NIN * HH, (long long)HH * 128);
    transpose_cvt_kernel<<<dim3(HH/32, HH/32, LL), 256, 0, stream>>>(
        W2, w2t, HH, HH, HH, (long long)HH * HH, (long long)HH * HH);
    transpose_cvt_kernel<<<dim3(HH/32, SPLIT/32, LL), 256, 0, stream>>>(
        Ws, wstt, HH, SPLIT, HH, (long long)HH * SPLIT, (long long)64 * HH);
    transpose_cvt_kernel<<<dim3(HH/32, SPLIT/32, LL), 256, 0, stream>>>(
        Wt, wstt + (size_t)SPLIT * HH, HH, SPLIT, HH, (long long)HH * SPLIT, (long long)64 * HH);

    init_ain_cond_kernel<<<BB * 96 / 256, 256, 0, stream>>>(cond, Ain);
    build_keep_kernel<<<BB * 32 / 256, 256, 0, stream>>>(xbuf, Ain, 0);

    for (int l = 0; l < LL; ++l) {
        const int off = l & 1;
        hipMemsetAsync(stat_sum, 0, 2 * 64 * sizeof(float), stream);

        for (int c = 0; c < BB / CH; ++c) {
            const int row0 = c * CH;

            // GEMM1: h1 = relu(Ain @ W1t^T + b1)   M=CH, K=128
            gemm_tiled<<<(CH / 128) * 4, 512, 0, stream>>>(
                Ain + (size_t)row0 * 128, w1t + (size_t)l * HH * 128,
                b1 + (size_t)l * HH, h1, 128);

            // GEMM2: h2 = relu(h1 @ W2t^T + b2)    M=CH, K=1024
            gemm_tiled<<<(CH / 128) * 4, 512, 0, stream>>>(
                h1, w2t + (size_t)l * HH * HH,
                b2 + (size_t)l * HH, h2, HH);

            // GEMM3 + coupling fused (BM=128, double-buffered)
            gemm3_coupling<<<CH / 128, 512, 0, stream>>>(
                h2, wstt + (size_t)l * 64 * HH,
                bs + (size_t)l * SPLIT, bt + (size_t)l * SPLIT,
                xbuf, out_ld, stat_sum, stat_sumsq, off, row0);
        }

        float* xout = (l == LL - 1) ? out_x : xbuf;
        u16* ain_next = (l < LL - 1) ? Ain : nullptr;
        normalize_kernel<<<(BB * DD / 4) / 256, 256, 0, stream>>>(
            xbuf, xout, stat_sum, stat_sumsq,
            bn_w + (size_t)l * DD, bn_b + (size_t)l * DD,
            out_ld, ain_next, (l + 1) & 1);
    }
}